// Round 4
// baseline (343.495 us; speedup 1.0000x reference)
//
#include <hip/hip_runtime.h>
#include <hip/hip_bf16.h>
#include <hip/hip_fp16.h>

#define B_  4
#define V_  256
#define H_  512
#define E_  32640   // V*(V-1)/2

typedef _Float16 half8 __attribute__((ext_vector_type(8)));
typedef float    f32x4 __attribute__((ext_vector_type(4)));

// Fast erf (Abramowitz-Stegun 7.1.26, |err| <= 1.5e-7), branchless.
__device__ __forceinline__ float gelu_f(float x) {
    float u = x * 0.70710678118654752f;
    float a = fabsf(u);
    float t = __builtin_amdgcn_rcpf(fmaf(0.3275911f, a, 1.0f));
    float poly = t * fmaf(t, fmaf(t, fmaf(t, fmaf(t, 1.061405429f, -1.453152027f),
                                          1.421413741f), -0.284496736f), 0.254829592f);
    float ex = __expf(-u * u);
    float erfa = fmaf(-poly, ex, 1.0f);
    float erfu = copysignf(erfa, u);
    return 0.5f * x * (1.0f + erfu);
}

__device__ __forceinline__ float wred_add(float v) {
    #pragma unroll
    for (int off = 32; off > 0; off >>= 1) v += __shfl_xor(v, off, 64);
    return v;
}

__device__ __forceinline__ void split16(float v, _Float16* hi, _Float16* lo) {
    _Float16 h = (_Float16)v;
    *hi = h; *lo = (_Float16)(v - (float)h);
}

// fragment-major offset for matrix with R rows: element (row, k) -> ((k/8)*R + row)*8 + k%8
__device__ __forceinline__ size_t fmoff(int R, int row, int k) {
    return ((size_t)(k >> 3) * R + row) * 8 + (k & 7);
}

// ---------------------------------------------------------------- one-shot setup
// seg0: x proj + frag split (524288) | seg1: w2f (131072) | seg2: etab (32640)
// seg3: in_w frag split (786432) | seg4: out_w frag split (262144) | seg5: w1 frag split (524288)
__global__ void k_setup(const float* __restrict__ verts, const float* __restrict__ wp,
                        const float* __restrict__ bp, float* __restrict__ x,
                        _Float16* __restrict__ xfh, _Float16* __restrict__ xfl,
                        const float* __restrict__ w2, _Float16* __restrict__ w2f,
                        int2* __restrict__ etab,
                        const float* __restrict__ in_w, _Float16* __restrict__ iwfh, _Float16* __restrict__ iwfl,
                        const float* __restrict__ out_w, _Float16* __restrict__ owfh, _Float16* __restrict__ owfl,
                        const float* __restrict__ w1, _Float16* __restrict__ w1fh, _Float16* __restrict__ w1fl) {
    int t = blockIdx.x * 256 + threadIdx.x;
    if (t < 524288) {
        int row = t >> 9, k = t & 511;
        const float* vr = verts + row * 3;
        const float* wr = wp + k * 3;
        float val = vr[0] * wr[0] + vr[1] * wr[1] + vr[2] * wr[2] + bp[k];
        x[t] = val;
        size_t fo = fmoff(1024, row, k);
        split16(val, xfh + fo, xfl + fo);
        return;
    }
    t -= 524288;
    if (t < 131072) {
        int col = t >> 9, k = t & 511;
        w2f[fmoff(256, col, k)] = (_Float16)w2[t];
        return;
    }
    t -= 131072;
    if (t < 32640) {
        double disc = (double)(2 * V_ - 1) * (2 * V_ - 1) - 8.0 * (double)t;
        int i = (int)((2 * V_ - 1 - sqrt(disc)) * 0.5);
        if (i < 0) i = 0;
        if (i > V_ - 2) i = V_ - 2;
        while (i < V_ - 2 && (i + 1) * (2 * V_ - 1 - (i + 1)) / 2 <= t) ++i;
        while (i > 0 && i * (2 * V_ - 1 - i) / 2 > t) --i;
        int j = t - i * (2 * V_ - 1 - i) / 2 + i + 1;
        etab[t] = make_int2(i, j);
        return;
    }
    t -= 32640;
    if (t < 786432) {
        int col = t >> 9, k = t & 511;
        size_t fo = fmoff(1536, col, k);
        split16(in_w[t], iwfh + fo, iwfl + fo);
        return;
    }
    t -= 786432;
    if (t < 262144) {
        int col = t >> 9, k = t & 511;
        size_t fo = fmoff(512, col, k);
        split16(out_w[t], owfh + fo, owfl + fo);
        return;
    }
    t -= 262144;
    if (t < 524288) {
        int col = t >> 9, k = t & 511;
        float v = (col < 512) ? w1[col * 1024 + k] : w1[(col - 512) * 1024 + 512 + k];
        size_t fo = fmoff(1024, col, k);
        split16(v, w1fh + fo, w1fl + fo);
    }
}

// ---------------------------------------------------------------- split-fp16 MFMA GEMM (frag-major in)
// M = 1024 fixed. MODE 0: C=qkv(+bias). MODE 1: C=x(+bias+res), frag split out.
// MODE 2: col<512 -> Amat(+bias)+Ahf ; col>=512 -> Bmat+Bhf
template<int MODE>
__global__ __launch_bounds__(256) void k_gemm_sp(
        const _Float16* __restrict__ Ahf, const _Float16* __restrict__ Alf,
        const _Float16* __restrict__ Whf, const _Float16* __restrict__ Wlf,
        const float* __restrict__ bias, const float* __restrict__ res,
        float* __restrict__ C, _Float16* __restrict__ Fh, _Float16* __restrict__ Fl,
        float* __restrict__ C2, _Float16* __restrict__ F2h, int N)
{
    const int tid = threadIdx.x;
    const int w = tid >> 6, l = tid & 63;
    const int lr = l & 15, lg = l >> 4;
    const int mg = w >> 1, ng = w & 1;
    const int row0 = blockIdx.y * 64 + mg * 32;
    const int col0 = blockIdx.x * 64 + ng * 32;

    f32x4 acc[2][2] = {};
    for (int kk = 0; kk < 16; ++kk) {
        const int kg = kk * 4 + lg;
        half8 ah[2], al[2], bh[2], bl[2];
        #pragma unroll
        for (int mi = 0; mi < 2; ++mi) {
            size_t off = ((size_t)kg * 1024 + row0 + mi * 16 + lr) * 8;
            ah[mi] = *(const half8*)(Ahf + off);
            al[mi] = *(const half8*)(Alf + off);
        }
        #pragma unroll
        for (int ni = 0; ni < 2; ++ni) {
            size_t off = ((size_t)kg * N + col0 + ni * 16 + lr) * 8;
            bh[ni] = *(const half8*)(Whf + off);
            bl[ni] = *(const half8*)(Wlf + off);
        }
        #pragma unroll
        for (int mi = 0; mi < 2; ++mi)
            #pragma unroll
            for (int ni = 0; ni < 2; ++ni) {
                acc[mi][ni] = __builtin_amdgcn_mfma_f32_16x16x32_f16(ah[mi], bh[ni], acc[mi][ni], 0, 0, 0);
                acc[mi][ni] = __builtin_amdgcn_mfma_f32_16x16x32_f16(ah[mi], bl[ni], acc[mi][ni], 0, 0, 0);
                acc[mi][ni] = __builtin_amdgcn_mfma_f32_16x16x32_f16(al[mi], bh[ni], acc[mi][ni], 0, 0, 0);
            }
    }
    #pragma unroll
    for (int mi = 0; mi < 2; ++mi)
        #pragma unroll
        for (int ni = 0; ni < 2; ++ni)
            #pragma unroll
            for (int r = 0; r < 4; ++r) {
                int row = row0 + mi * 16 + lg * 4 + r;
                int col = col0 + ni * 16 + lr;
                float v = acc[mi][ni][r];
                if (MODE == 0) {
                    C[(size_t)row * N + col] = v + bias[col];
                } else if (MODE == 1) {
                    size_t idx = (size_t)row * 512 + col;
                    v += bias[col] + res[idx];
                    C[idx] = v;
                    size_t fo = fmoff(1024, row, col);
                    split16(v, Fh + fo, Fl + fo);
                } else {
                    if (col < 512) {
                        size_t idx = (size_t)row * 512 + col;
                        v += bias[col];
                        C[idx] = v;
                        Fh[fmoff(1024, row, col)] = (_Float16)v;
                    } else {
                        int c2 = col - 512;
                        C2[(size_t)row * 512 + c2] = v;
                        F2h[fmoff(1024, row, c2)] = (_Float16)v;
                    }
                }
            }
}

// ---------------------------------------------------------------- attention (fp32, two-pass group softmax)
// grid = B*NH*8 (query-groups of 32), 512 thr = 32 q x 16 key-groups of 16
__global__ __launch_bounds__(512) void k_attn(const float* __restrict__ qkv,
                                              _Float16* __restrict__ cfh,
                                              _Float16* __restrict__ cfl) {
    const int bid = blockIdx.x;
    const int qg = bid & 7, h = (bid >> 3) & 7, b = bid >> 6;
    const int tid = threadIdx.x;
    const int q = tid & 31, g = tid >> 5;          // g = 0..15
    const int qi = qg * 32 + q;
    const float* qrow = qkv + ((size_t)(b * V_ + qi)) * 1536 + h * 64;
    float qreg[64];
    #pragma unroll
    for (int dd = 0; dd < 16; ++dd) {
        f32x4 t4 = *(const f32x4*)(qrow + dd * 4);
        qreg[dd*4+0]=t4[0]; qreg[dd*4+1]=t4[1]; qreg[dd*4+2]=t4[2]; qreg[dd*4+3]=t4[3];
    }
    // pass 1: 16 scores
    float sc[16];
    #pragma unroll
    for (int kk = 0; kk < 16; ++kk) {
        const int kr = g * 16 + kk;
        const float* krow = qkv + ((size_t)(b * V_ + kr)) * 1536 + 512 + h * 64;
        float s = 0.0f;
        #pragma unroll
        for (int dd = 0; dd < 16; ++dd) {
            f32x4 kv = *(const f32x4*)(krow + dd * 4);
            s += qreg[dd*4+0]*kv[0] + qreg[dd*4+1]*kv[1] + qreg[dd*4+2]*kv[2] + qreg[dd*4+3]*kv[3];
        }
        sc[kk] = s * 0.125f;
    }
    float m = sc[0];
    #pragma unroll
    for (int kk = 1; kk < 16; ++kk) m = fmaxf(m, sc[kk]);
    float lsum = 0.0f;
    #pragma unroll
    for (int kk = 0; kk < 16; ++kk) { sc[kk] = __expf(sc[kk] - m); lsum += sc[kk]; }
    // pass 2: PV (unnormalized)
    float cacc[64];
    #pragma unroll
    for (int d = 0; d < 64; ++d) cacc[d] = 0.0f;
    #pragma unroll
    for (int kk = 0; kk < 16; ++kk) {
        const int kr = g * 16 + kk;
        const float* vrow = qkv + ((size_t)(b * V_ + kr)) * 1536 + 1024 + h * 64;
        const float p = sc[kk];
        #pragma unroll
        for (int dd = 0; dd < 16; ++dd) {
            f32x4 vv = *(const f32x4*)(vrow + dd * 4);
            #pragma unroll
            for (int c = 0; c < 4; ++c) cacc[dd*4+c] += p * vv[c];
        }
    }
    __shared__ float mls[16][32][2];
    __shared__ float cbuf[16][32][16];
    mls[g][q][0] = m; mls[g][q][1] = lsum;
    __syncthreads();
    float M = -1e30f;
    #pragma unroll
    for (int gg = 0; gg < 16; ++gg) M = fmaxf(M, mls[gg][q][0]);
    float L = 0.0f;
    #pragma unroll
    for (int gg = 0; gg < 16; ++gg) L += mls[gg][q][1] * __expf(mls[gg][q][0] - M);
    const float myscale = __expf(m - M) / L;
    for (int c = 0; c < 4; ++c) {
        #pragma unroll
        for (int d = 0; d < 16; ++d) cbuf[g][q][d] = cacc[c * 16 + d] * myscale;
        __syncthreads();
        {
            int qq = tid >> 4, d = tid & 15;
            float sum = 0.0f;
            #pragma unroll
            for (int gg = 0; gg < 16; ++gg) sum += cbuf[gg][qq][d];
            int row = b * 256 + qg * 32 + qq;
            int col = h * 64 + c * 16 + d;
            size_t fo = fmoff(1024, row, col);
            split16(sum, cfh + fo, cfl + fo);
        }
        __syncthreads();
    }
}

// ---------------------------------------------------------------- pair dots + row stats (fused)
// blocks 0..255: P tiles. blocks 256..383: row stats (16 rows each).
__global__ __launch_bounds__(256) void k_pair_stats(
        const _Float16* __restrict__ Ahf, const _Float16* __restrict__ Bhf,
        const float* __restrict__ Amat, const float* __restrict__ Bmat,
        float* __restrict__ P, float2* __restrict__ statsA, float2* __restrict__ statsB) {
    const int bid = blockIdx.x;
    const int tid = threadIdx.x;
    if (bid < 256) {
        const int t = bid * 4 + (tid >> 6);
        const int b = t >> 8, tt = t & 255;
        const int i0 = (tt >> 4) * 16, j0 = (tt & 15) * 16;
        const int l = tid & 63, lr = l & 15, lg = l >> 4;
        f32x4 acc = {};
        for (int kk = 0; kk < 16; ++kk) {
            const int kg = kk * 4 + lg;
            half8 af = *(const half8*)(Ahf + ((size_t)kg * 1024 + b * 256 + i0 + lr) * 8);
            half8 bf = *(const half8*)(Bhf + ((size_t)kg * 1024 + b * 256 + j0 + lr) * 8);
            acc = __builtin_amdgcn_mfma_f32_16x16x32_f16(af, bf, acc, 0, 0, 0);
        }
        #pragma unroll
        for (int r = 0; r < 4; ++r)
            P[((size_t)b << 16) + (size_t)(i0 + lg * 4 + r) * 256 + j0 + lr] = acc[r];
    } else {
        const int sid = bid - 256;                  // 0..127
        const int slice = tid >> 4, lane = tid & 15;
        const int m = sid * 16 + slice;             // 0..2047
        const float* src = (m < 1024 ? Amat + (size_t)m * 512 : Bmat + (size_t)(m - 1024) * 512);
        float s = 0.0f, sq = 0.0f;
        #pragma unroll
        for (int i = 0; i < 8; ++i) {
            f32x4 v = *(const f32x4*)(src + i * 64 + lane * 4);
            s  += v[0] + v[1] + v[2] + v[3];
            sq += v[0]*v[0] + v[1]*v[1] + v[2]*v[2] + v[3]*v[3];
        }
        #pragma unroll
        for (int off = 8; off > 0; off >>= 1) {
            s  += __shfl_xor(s, off, 64);
            sq += __shfl_xor(sq, off, 64);
        }
        if (lane == 0) {
            if (m < 1024) statsA[m] = make_float2(s, sq);
            else          statsB[m - 1024] = make_float2(s, sq);
        }
    }
}

// ---------------------------------------------------------------- fused edge MLP
// grid = B*510 (64 edges/block, XCD-swizzled), 512 thr = 8 waves, 64KB dynamic LDS.
__global__ __launch_bounds__(512, 4) void k_edge(
        const float* __restrict__ Am, const float* __restrict__ Bm,
        const _Float16* __restrict__ w2f,
        const float* __restrict__ g1, const float* __restrict__ be1,
        const float* __restrict__ b2, const float* __restrict__ g2,
        const float* __restrict__ be2, const float* __restrict__ w3,
        const float* __restrict__ b3, const int2* __restrict__ etab,
        const float2* __restrict__ statsA, const float2* __restrict__ statsB,
        const float* __restrict__ P, float* __restrict__ out)
{
    extern __shared__ unsigned char smem[];   // 65536 B
    const int tid = threadIdx.x;
    const int w = tid >> 6;
    const int l = tid & 63;
    // XCD-aware swizzle: 2040 = 8 XCDs x 255 contiguous chunks
    const int bid0 = blockIdx.x;
    const int swz = (bid0 & 7) * 255 + (bid0 >> 3);
    const int b  = swz / 510;
    const int eb = swz % 510;

    // ---- Phase A: g = gelu(LN1(A_i + B_j)) -> fp16 LDS in MFMA-fragment order
    {
        const int el = l >> 3;
        const int kq = l & 7;
        const int e  = w * 8 + el;
        int2 ij = etab[eb * 64 + e];
        float2 sa = statsA[b * 256 + ij.x];
        float2 sb = statsB[b * 256 + ij.y];
        float pij = P[((size_t)b << 16) + ((size_t)ij.x << 8) + ij.y];
        float mean = (sa.x + sb.x) * (1.0f / 512.0f);
        float ex2  = (sa.y + sb.y + 2.0f * pij) * (1.0f / 512.0f);
        float rstd = rsqrtf(ex2 - mean * mean + 1e-5f);
        const float* ar = Am + (((size_t)(b * 256 + ij.x)) << 9);
        const float* br = Bm + (((size_t)(b * 256 + ij.y)) << 9);
        #pragma unroll
        for (int t = 0; t < 8; ++t) {
            const int kg = kq + 8 * t;
            const int k0 = kg * 8;
            f32x4 a0 = *(const f32x4*)(ar + k0);
            f32x4 a1 = *(const f32x4*)(ar + k0 + 4);
            f32x4 c0 = *(const f32x4*)(br + k0);
            f32x4 c1 = *(const f32x4*)(br + k0 + 4);
            f32x4 ga = *(const f32x4*)(g1 + k0);
            f32x4 gb = *(const f32x4*)(g1 + k0 + 4);
            f32x4 ea = *(const f32x4*)(be1 + k0);
            f32x4 ebv= *(const f32x4*)(be1 + k0 + 4);
            half8 hv;
            #pragma unroll
            for (int c = 0; c < 4; ++c) {
                float xa = ((a0[c] + c0[c]) - mean) * rstd * ga[c] + ea[c];
                float xb = ((a1[c] + c1[c]) - mean) * rstd * gb[c] + ebv[c];
                hv[c]     = (_Float16)gelu_f(xa);
                hv[c + 4] = (_Float16)gelu_f(xb);
            }
            *(half8*)(smem + kg * 1024 + ((e ^ (kg & 7)) << 4)) = hv;
        }
    }
    __syncthreads();

    // ---- Phase B: 4 m-tiles x 2 n-tiles per wave (wave owns cols [32w,32w+32))
    f32x4 acc[4][2] = {};
    const int lg = l >> 4, lr = l & 15;
    const int col0 = w * 32;
    #pragma unroll
    for (int kk = 0; kk < 16; ++kk) {
        const int kg = kk * 4 + lg;
        half8 bf[2];
        #pragma unroll
        for (int ni = 0; ni < 2; ++ni)
            bf[ni] = *(const half8*)(w2f + ((size_t)kg * 256 + col0 + ni * 16 + lr) * 8);
        half8 af[4];
        #pragma unroll
        for (int mi = 0; mi < 4; ++mi)
            af[mi] = *(const half8*)(smem + kg * 1024 + (((mi * 16 + lr) ^ (kg & 7)) << 4));
        #pragma unroll
        for (int mi = 0; mi < 4; ++mi)
            #pragma unroll
            for (int ni = 0; ni < 2; ++ni)
                acc[mi][ni] = __builtin_amdgcn_mfma_f32_16x16x32_f16(af[mi], bf[ni], acc[mi][ni], 0, 0, 0);
    }
    __syncthreads();

    // ---- h2 (+b2) -> LDS as [64 edges][256 cols] f32
    #pragma unroll
    for (int ni = 0; ni < 2; ++ni) {
        const int col = col0 + ni * 16 + lr;
        const float bb = b2[col];
        #pragma unroll
        for (int mi = 0; mi < 4; ++mi)
            #pragma unroll
            for (int r = 0; r < 4; ++r) {
                const int e = mi * 16 + lg * 4 + r;
                *(float*)(smem + e * 1024 + col * 4) = acc[mi][ni][r] + bb;
            }
    }
    __syncthreads();

    // ---- Phase C: LN2 + gelu + dot(w3) + sigmoid
    {
        const int o0 = l * 4;
        f32x4 g2v = *(const f32x4*)(g2 + o0);
        f32x4 e2v = *(const f32x4*)(be2 + o0);
        f32x4 w3v = *(const f32x4*)(w3 + o0);
        float b3s = b3[0];
        #pragma unroll
        for (int el = 0; el < 8; ++el) {
            const int e = w * 8 + el;
            f32x4 h = *(const f32x4*)(smem + e * 1024 + o0 * 4);
            float s  = h[0] + h[1] + h[2] + h[3];
            float sq = h[0]*h[0] + h[1]*h[1] + h[2]*h[2] + h[3]*h[3];
            s = wred_add(s); sq = wred_add(sq);
            float mean = s * (1.0f / 256.0f);
            float rstd = rsqrtf(sq * (1.0f / 256.0f) - mean * mean + 1e-5f);
            float part = 0.0f;
            #pragma unroll
            for (int c = 0; c < 4; ++c) {
                float xx = (h[c] - mean) * rstd * g2v[c] + e2v[c];
                part += gelu_f(xx) * w3v[c];
            }
            part = wred_add(part);
            if (l == 0)
                out[(size_t)b * E_ + eb * 64 + e] = 1.0f / (1.0f + __expf(-(part + b3s)));
        }
    }
}

// ---------------------------------------------------------------- launch
extern "C" void kernel_launch(void* const* d_in, const int* in_sizes, int n_in,
                              void* d_out, int out_size, void* d_ws, size_t ws_size,
                              hipStream_t stream) {
    const float* verts = (const float*)d_in[0];
    const float* wp    = (const float*)d_in[1];
    const float* bp    = (const float*)d_in[2];
    const float* in_w  = (const float*)d_in[3];
    const float* in_b  = (const float*)d_in[4];
    const float* out_w = (const float*)d_in[5];
    const float* out_b = (const float*)d_in[6];
    const float* w1    = (const float*)d_in[7];
    const float* b1    = (const float*)d_in[8];
    const float* g1    = (const float*)d_in[9];
    const float* be1   = (const float*)d_in[10];
    const float* w2    = (const float*)d_in[11];
    const float* b2    = (const float*)d_in[12];
    const float* g2    = (const float*)d_in[13];
    const float* be2   = (const float*)d_in[14];
    const float* w3    = (const float*)d_in[15];
    const float* b3    = (const float*)d_in[16];
    float* out = (float*)d_out;

    const size_t MB = 1 << 20;
    char* W = (char*)d_ws;
    float*    x     = (float*)(W + 0);                 // 2MB
    _Float16* xfh   = (_Float16*)(W + 2*MB);           // 1MB (frag-major)
    _Float16* xfl   = (_Float16*)(W + 3*MB);           // 1MB
    float*    qkv   = (float*)(W + 4*MB);              // 6MB (dead after attn)
    float*    Amat  = (float*)(W + 4*MB);              // 2MB (reuse qkv)
    float*    Bmat  = (float*)(W + 6*MB);              // 2MB
    _Float16* Ahf   = (_Float16*)(W + 8*MB);           // 1MB (frag-major)
    _Float16* Bhf   = (_Float16*)(W + 9*MB);           // 1MB
    _Float16* ctxfh = (_Float16*)(W + 10*MB);          // 1MB (frag-major)
    _Float16* ctxfl = (_Float16*)(W + 11*MB);          // 1MB
    _Float16* w2f   = (_Float16*)(W + 12*MB);          // 256KB
    int2*     etab  = (int2*)(W + 12*MB + 256*1024);   // 256KB
    float2*   statsA= (float2*)(W + 12*MB + 512*1024); // 8KB
    float2*   statsB= (float2*)(W + 12*MB + 520*1024); // 8KB
    _Float16* iwfh  = (_Float16*)(W + 13*MB);          // 1.5MB
    _Float16* iwfl  = (_Float16*)(W + 13*MB + 1536*1024);
    _Float16* owfh  = (_Float16*)(W + 16*MB);          // 0.5MB
    _Float16* owfl  = (_Float16*)(W + 16*MB + 512*1024);
    _Float16* w1fh  = (_Float16*)(W + 17*MB);          // 1MB
    _Float16* w1fl  = (_Float16*)(W + 18*MB);          // 1MB
    float*    P     = (float*)(W + 19*MB);             // 1MB

    k_setup<<<dim3(8832), dim3(256), 0, stream>>>(verts, wp, bp, x, xfh, xfl,
                                                  w2, w2f, etab, in_w, iwfh, iwfl,
                                                  out_w, owfh, owfl, w1, w1fh, w1fl);
    // qkv = x @ in_w^T + in_b
    k_gemm_sp<0><<<dim3(24, 16), dim3(256), 0, stream>>>(xfh, xfl, iwfh, iwfl, in_b, nullptr,
                                                         qkv, nullptr, nullptr, nullptr, nullptr, 1536);
    k_attn<<<dim3(256), dim3(512), 0, stream>>>(qkv, ctxfh, ctxfl);
    // x = x + ctx @ out_w^T + out_b ; refresh xfh/xfl
    k_gemm_sp<1><<<dim3(8, 16), dim3(256), 0, stream>>>(ctxfh, ctxfl, owfh, owfl, out_b, x,
                                                        x, xfh, xfl, nullptr, nullptr, 512);
    // Amat = x @ w1[:, :512]^T + b1 ; Bmat = x @ w1[:, 512:]^T
    k_gemm_sp<2><<<dim3(16, 16), dim3(256), 0, stream>>>(xfh, xfl, w1fh, w1fl, b1, nullptr,
                                                         Amat, Ahf, nullptr, Bmat, Bhf, 1024);
    k_pair_stats<<<dim3(384), dim3(256), 0, stream>>>(Ahf, Bhf, Amat, Bmat, P, statsA, statsB);
    k_edge<<<dim3(B_ * 510), dim3(512), 65536, stream>>>(Amat, Bmat, w2f,
                                                         g1, be1, b2, g2, be2, w3, b3,
                                                         etab, statsA, statsB, P, out);
}

// Round 5
// 314.734 us; speedup vs baseline: 1.0914x; 1.0914x over previous
//
#include <hip/hip_runtime.h>
#include <hip/hip_bf16.h>
#include <hip/hip_fp16.h>

#define B_  4
#define V_  256
#define H_  512
#define E_  32640   // V*(V-1)/2

typedef _Float16 half8 __attribute__((ext_vector_type(8)));
typedef float    f32x4 __attribute__((ext_vector_type(4)));

// Fast erf (Abramowitz-Stegun 7.1.26, |err| <= 1.5e-7), branchless.
__device__ __forceinline__ float gelu_f(float x) {
    float u = x * 0.70710678118654752f;
    float a = fabsf(u);
    float t = __builtin_amdgcn_rcpf(fmaf(0.3275911f, a, 1.0f));
    float poly = t * fmaf(t, fmaf(t, fmaf(t, fmaf(t, 1.061405429f, -1.453152027f),
                                          1.421413741f), -0.284496736f), 0.254829592f);
    float ex = __expf(-u * u);
    float erfa = fmaf(-poly, ex, 1.0f);
    float erfu = copysignf(erfa, u);
    return 0.5f * x * (1.0f + erfu);
}

__device__ __forceinline__ float wred_add(float v) {
    #pragma unroll
    for (int off = 32; off > 0; off >>= 1) v += __shfl_xor(v, off, 64);
    return v;
}

__device__ __forceinline__ void split16(float v, _Float16* hi, _Float16* lo) {
    _Float16 h = (_Float16)v;
    *hi = h; *lo = (_Float16)(v - (float)h);
}

// fragment-major offset for matrix with R rows: element (row, k) -> ((k/8)*R + row)*8 + k%8
__device__ __forceinline__ size_t fmoff(int R, int row, int k) {
    return ((size_t)(k >> 3) * R + row) * 8 + (k & 7);
}

// ---------------------------------------------------------------- one-shot setup
__global__ void k_setup(const float* __restrict__ verts, const float* __restrict__ wp,
                        const float* __restrict__ bp, float* __restrict__ x,
                        _Float16* __restrict__ xfh, _Float16* __restrict__ xfl,
                        const float* __restrict__ w2, _Float16* __restrict__ w2f,
                        int2* __restrict__ etab,
                        const float* __restrict__ in_w, _Float16* __restrict__ iwfh, _Float16* __restrict__ iwfl,
                        const float* __restrict__ out_w, _Float16* __restrict__ owfh, _Float16* __restrict__ owfl,
                        const float* __restrict__ w1, _Float16* __restrict__ w1fh, _Float16* __restrict__ w1fl) {
    int t = blockIdx.x * 256 + threadIdx.x;
    if (t < 524288) {
        int row = t >> 9, k = t & 511;
        const float* vr = verts + row * 3;
        const float* wr = wp + k * 3;
        float val = vr[0] * wr[0] + vr[1] * wr[1] + vr[2] * wr[2] + bp[k];
        x[t] = val;
        size_t fo = fmoff(1024, row, k);
        split16(val, xfh + fo, xfl + fo);
        return;
    }
    t -= 524288;
    if (t < 131072) {
        int col = t >> 9, k = t & 511;
        w2f[fmoff(256, col, k)] = (_Float16)w2[t];
        return;
    }
    t -= 131072;
    if (t < 32640) {
        double disc = (double)(2 * V_ - 1) * (2 * V_ - 1) - 8.0 * (double)t;
        int i = (int)((2 * V_ - 1 - sqrt(disc)) * 0.5);
        if (i < 0) i = 0;
        if (i > V_ - 2) i = V_ - 2;
        while (i < V_ - 2 && (i + 1) * (2 * V_ - 1 - (i + 1)) / 2 <= t) ++i;
        while (i > 0 && i * (2 * V_ - 1 - i) / 2 > t) --i;
        int j = t - i * (2 * V_ - 1 - i) / 2 + i + 1;
        etab[t] = make_int2(i, j);
        return;
    }
    t -= 32640;
    if (t < 786432) {
        int col = t >> 9, k = t & 511;
        size_t fo = fmoff(1536, col, k);
        split16(in_w[t], iwfh + fo, iwfl + fo);
        return;
    }
    t -= 786432;
    if (t < 262144) {
        int col = t >> 9, k = t & 511;
        size_t fo = fmoff(512, col, k);
        split16(out_w[t], owfh + fo, owfl + fo);
        return;
    }
    t -= 262144;
    if (t < 524288) {
        int col = t >> 9, k = t & 511;
        float v = (col < 512) ? w1[col * 1024 + k] : w1[(col - 512) * 1024 + 512 + k];
        size_t fo = fmoff(1024, col, k);
        split16(v, w1fh + fo, w1fl + fo);
    }
}

// ---------------------------------------------------------------- split-fp16 MFMA GEMM (frag-major in)
template<int MODE>
__global__ __launch_bounds__(256) void k_gemm_sp(
        const _Float16* __restrict__ Ahf, const _Float16* __restrict__ Alf,
        const _Float16* __restrict__ Whf, const _Float16* __restrict__ Wlf,
        const float* __restrict__ bias, const float* __restrict__ res,
        float* __restrict__ C, _Float16* __restrict__ Fh, _Float16* __restrict__ Fl,
        float* __restrict__ C2, _Float16* __restrict__ F2h, int N)
{
    const int tid = threadIdx.x;
    const int w = tid >> 6, l = tid & 63;
    const int lr = l & 15, lg = l >> 4;
    const int mg = w >> 1, ng = w & 1;
    const int row0 = blockIdx.y * 64 + mg * 32;
    const int col0 = blockIdx.x * 64 + ng * 32;

    f32x4 acc[2][2] = {};
    for (int kk = 0; kk < 16; ++kk) {
        const int kg = kk * 4 + lg;
        half8 ah[2], al[2], bh[2], bl[2];
        #pragma unroll
        for (int mi = 0; mi < 2; ++mi) {
            size_t off = ((size_t)kg * 1024 + row0 + mi * 16 + lr) * 8;
            ah[mi] = *(const half8*)(Ahf + off);
            al[mi] = *(const half8*)(Alf + off);
        }
        #pragma unroll
        for (int ni = 0; ni < 2; ++ni) {
            size_t off = ((size_t)kg * N + col0 + ni * 16 + lr) * 8;
            bh[ni] = *(const half8*)(Whf + off);
            bl[ni] = *(const half8*)(Wlf + off);
        }
        #pragma unroll
        for (int mi = 0; mi < 2; ++mi)
            #pragma unroll
            for (int ni = 0; ni < 2; ++ni) {
                acc[mi][ni] = __builtin_amdgcn_mfma_f32_16x16x32_f16(ah[mi], bh[ni], acc[mi][ni], 0, 0, 0);
                acc[mi][ni] = __builtin_amdgcn_mfma_f32_16x16x32_f16(ah[mi], bl[ni], acc[mi][ni], 0, 0, 0);
                acc[mi][ni] = __builtin_amdgcn_mfma_f32_16x16x32_f16(al[mi], bh[ni], acc[mi][ni], 0, 0, 0);
            }
    }
    #pragma unroll
    for (int mi = 0; mi < 2; ++mi)
        #pragma unroll
        for (int ni = 0; ni < 2; ++ni)
            #pragma unroll
            for (int r = 0; r < 4; ++r) {
                int row = row0 + mi * 16 + lg * 4 + r;
                int col = col0 + ni * 16 + lr;
                float v = acc[mi][ni][r];
                if (MODE == 0) {
                    C[(size_t)row * N + col] = v + bias[col];
                } else if (MODE == 1) {
                    size_t idx = (size_t)row * 512 + col;
                    v += bias[col] + res[idx];
                    C[idx] = v;
                    size_t fo = fmoff(1024, row, col);
                    split16(v, Fh + fo, Fl + fo);
                } else {
                    if (col < 512) {
                        size_t idx = (size_t)row * 512 + col;
                        v += bias[col];
                        C[idx] = v;
                        Fh[fmoff(1024, row, col)] = (_Float16)v;
                    } else {
                        int c2 = col - 512;
                        C2[(size_t)row * 512 + c2] = v;
                        F2h[fmoff(1024, row, c2)] = (_Float16)v;
                    }
                }
            }
}

// ---------------------------------------------------------------- attention
// grid = B*NH*8 (query-groups of 32), 256 threads = 32 q x 8 key-groups of 32.
// Online softmax, ~170 VGPR with 256-thread launch bounds -> no scratch spill.
__global__ __launch_bounds__(256) void k_attn(const float* __restrict__ qkv,
                                              _Float16* __restrict__ cfh,
                                              _Float16* __restrict__ cfl) {
    const int bid = blockIdx.x;
    const int qg = bid & 7, h = (bid >> 3) & 7, b = bid >> 6;
    const int tid = threadIdx.x;
    const int q = tid & 31, g = tid >> 5;          // g = 0..7
    const int qi = qg * 32 + q;
    const float* qrow = qkv + ((size_t)(b * V_ + qi)) * 1536 + h * 64;
    float qreg[64];
    #pragma unroll
    for (int dd = 0; dd < 16; ++dd) {
        f32x4 t4 = *(const f32x4*)(qrow + dd * 4);
        qreg[dd*4+0]=t4[0]; qreg[dd*4+1]=t4[1]; qreg[dd*4+2]=t4[2]; qreg[dd*4+3]=t4[3];
    }
    float m = -1e30f, lsum = 0.0f;
    float cacc[64];
    #pragma unroll
    for (int d = 0; d < 64; ++d) cacc[d] = 0.0f;
    for (int kk = 0; kk < 32; ++kk) {
        const int kr = g * 32 + kk;
        const float* krow = qkv + ((size_t)(b * V_ + kr)) * 1536 + 512 + h * 64;
        float s = 0.0f;
        #pragma unroll
        for (int dd = 0; dd < 16; ++dd) {
            f32x4 kv = *(const f32x4*)(krow + dd * 4);
            s += qreg[dd*4+0]*kv[0] + qreg[dd*4+1]*kv[1] + qreg[dd*4+2]*kv[2] + qreg[dd*4+3]*kv[3];
        }
        s *= 0.125f;
        float mn = fmaxf(m, s);
        float scale = __expf(m - mn);
        float p = __expf(s - mn);
        lsum = lsum * scale + p;
        const float* vrow = qkv + ((size_t)(b * V_ + kr)) * 1536 + 1024 + h * 64;
        #pragma unroll
        for (int dd = 0; dd < 16; ++dd) {
            f32x4 vv = *(const f32x4*)(vrow + dd * 4);
            #pragma unroll
            for (int c = 0; c < 4; ++c)
                cacc[dd*4+c] = cacc[dd*4+c] * scale + p * vv[c];
        }
        m = mn;
    }
    __shared__ float mls[8][32][2];
    __shared__ float cbuf[8][32][16];
    mls[g][q][0] = m; mls[g][q][1] = lsum;
    __syncthreads();
    float M = -1e30f;
    #pragma unroll
    for (int gg = 0; gg < 8; ++gg) M = fmaxf(M, mls[gg][q][0]);
    float L = 0.0f;
    #pragma unroll
    for (int gg = 0; gg < 8; ++gg) L += mls[gg][q][1] * __expf(mls[gg][q][0] - M);
    const float myscale = __expf(m - M) / L;
    for (int c = 0; c < 4; ++c) {
        #pragma unroll
        for (int d = 0; d < 16; ++d) cbuf[g][q][d] = cacc[c * 16 + d] * myscale;
        __syncthreads();
        for (int idx = tid; idx < 512; idx += 256) {
            int qq = idx >> 4, d = idx & 15;
            float sum = 0.0f;
            #pragma unroll
            for (int gg = 0; gg < 8; ++gg) sum += cbuf[gg][qq][d];
            int row = b * 256 + qg * 32 + qq;
            int col = h * 64 + c * 16 + d;
            size_t fo = fmoff(1024, row, col);
            split16(sum, cfh + fo, cfl + fo);
        }
        __syncthreads();
    }
}

// ---------------------------------------------------------------- pair dots + row stats (fused)
__global__ __launch_bounds__(256) void k_pair_stats(
        const _Float16* __restrict__ Ahf, const _Float16* __restrict__ Bhf,
        const float* __restrict__ Amat, const float* __restrict__ Bmat,
        float* __restrict__ P, float2* __restrict__ statsA, float2* __restrict__ statsB) {
    const int bid = blockIdx.x;
    const int tid = threadIdx.x;
    if (bid < 256) {
        const int t = bid * 4 + (tid >> 6);
        const int b = t >> 8, tt = t & 255;
        const int i0 = (tt >> 4) * 16, j0 = (tt & 15) * 16;
        const int l = tid & 63, lr = l & 15, lg = l >> 4;
        f32x4 acc = {};
        for (int kk = 0; kk < 16; ++kk) {
            const int kg = kk * 4 + lg;
            half8 af = *(const half8*)(Ahf + ((size_t)kg * 1024 + b * 256 + i0 + lr) * 8);
            half8 bf = *(const half8*)(Bhf + ((size_t)kg * 1024 + b * 256 + j0 + lr) * 8);
            acc = __builtin_amdgcn_mfma_f32_16x16x32_f16(af, bf, acc, 0, 0, 0);
        }
        #pragma unroll
        for (int r = 0; r < 4; ++r)
            P[((size_t)b << 16) + (size_t)(i0 + lg * 4 + r) * 256 + j0 + lr] = acc[r];
    } else {
        const int sid = bid - 256;
        const int slice = tid >> 4, lane = tid & 15;
        const int m = sid * 16 + slice;
        const float* src = (m < 1024 ? Amat + (size_t)m * 512 : Bmat + (size_t)(m - 1024) * 512);
        float s = 0.0f, sq = 0.0f;
        #pragma unroll
        for (int i = 0; i < 8; ++i) {
            f32x4 v = *(const f32x4*)(src + i * 64 + lane * 4);
            s  += v[0] + v[1] + v[2] + v[3];
            sq += v[0]*v[0] + v[1]*v[1] + v[2]*v[2] + v[3]*v[3];
        }
        #pragma unroll
        for (int off = 8; off > 0; off >>= 1) {
            s  += __shfl_xor(s, off, 64);
            sq += __shfl_xor(sq, off, 64);
        }
        if (lane == 0) {
            if (m < 1024) statsA[m] = make_float2(s, sq);
            else          statsB[m - 1024] = make_float2(s, sq);
        }
    }
}

// ---------------------------------------------------------------- fused edge MLP
__global__ __launch_bounds__(512, 4) void k_edge(
        const float* __restrict__ Am, const float* __restrict__ Bm,
        const _Float16* __restrict__ w2f,
        const float* __restrict__ g1, const float* __restrict__ be1,
        const float* __restrict__ b2, const float* __restrict__ g2,
        const float* __restrict__ be2, const float* __restrict__ w3,
        const float* __restrict__ b3, const int2* __restrict__ etab,
        const float2* __restrict__ statsA, const float2* __restrict__ statsB,
        const float* __restrict__ P, float* __restrict__ out)
{
    extern __shared__ unsigned char smem[];   // 65536 B
    const int tid = threadIdx.x;
    const int w = tid >> 6;
    const int l = tid & 63;
    const int bid0 = blockIdx.x;
    const int swz = (bid0 & 7) * 255 + (bid0 >> 3);
    const int b  = swz / 510;
    const int eb = swz % 510;

    // ---- Phase A: g = gelu(LN1(A_i + B_j)) -> fp16 LDS in MFMA-fragment order
    {
        const int el = l >> 3;
        const int kq = l & 7;
        const int e  = w * 8 + el;
        int2 ij = etab[eb * 64 + e];
        float2 sa = statsA[b * 256 + ij.x];
        float2 sb = statsB[b * 256 + ij.y];
        float pij = P[((size_t)b << 16) + ((size_t)ij.x << 8) + ij.y];
        float mean = (sa.x + sb.x) * (1.0f / 512.0f);
        float ex2  = (sa.y + sb.y + 2.0f * pij) * (1.0f / 512.0f);
        float rstd = rsqrtf(ex2 - mean * mean + 1e-5f);
        const float* ar = Am + (((size_t)(b * 256 + ij.x)) << 9);
        const float* br = Bm + (((size_t)(b * 256 + ij.y)) << 9);
        #pragma unroll
        for (int t = 0; t < 8; ++t) {
            const int kg = kq + 8 * t;
            const int k0 = kg * 8;
            f32x4 a0 = *(const f32x4*)(ar + k0);
            f32x4 a1 = *(const f32x4*)(ar + k0 + 4);
            f32x4 c0 = *(const f32x4*)(br + k0);
            f32x4 c1 = *(const f32x4*)(br + k0 + 4);
            f32x4 ga = *(const f32x4*)(g1 + k0);
            f32x4 gb = *(const f32x4*)(g1 + k0 + 4);
            f32x4 ea = *(const f32x4*)(be1 + k0);
            f32x4 ebv= *(const f32x4*)(be1 + k0 + 4);
            half8 hv;
            #pragma unroll
            for (int c = 0; c < 4; ++c) {
                float xa = ((a0[c] + c0[c]) - mean) * rstd * ga[c] + ea[c];
                float xb = ((a1[c] + c1[c]) - mean) * rstd * gb[c] + ebv[c];
                hv[c]     = (_Float16)gelu_f(xa);
                hv[c + 4] = (_Float16)gelu_f(xb);
            }
            *(half8*)(smem + kg * 1024 + ((e ^ (kg & 7)) << 4)) = hv;
        }
    }
    __syncthreads();

    // ---- Phase B: 4 m-tiles x 2 n-tiles per wave (wave owns cols [32w,32w+32))
    f32x4 acc[4][2] = {};
    const int lg = l >> 4, lr = l & 15;
    const int col0 = w * 32;
    #pragma unroll
    for (int kk = 0; kk < 16; ++kk) {
        const int kg = kk * 4 + lg;
        half8 bf[2];
        #pragma unroll
        for (int ni = 0; ni < 2; ++ni)
            bf[ni] = *(const half8*)(w2f + ((size_t)kg * 256 + col0 + ni * 16 + lr) * 8);
        half8 af[4];
        #pragma unroll
        for (int mi = 0; mi < 4; ++mi)
            af[mi] = *(const half8*)(smem + kg * 1024 + (((mi * 16 + lr) ^ (kg & 7)) << 4));
        #pragma unroll
        for (int mi = 0; mi < 4; ++mi)
            #pragma unroll
            for (int ni = 0; ni < 2; ++ni)
                acc[mi][ni] = __builtin_amdgcn_mfma_f32_16x16x32_f16(af[mi], bf[ni], acc[mi][ni], 0, 0, 0);
    }
    __syncthreads();

    // ---- h2 (+b2) -> LDS as [64 edges][256 cols] f32
    #pragma unroll
    for (int ni = 0; ni < 2; ++ni) {
        const int col = col0 + ni * 16 + lr;
        const float bb = b2[col];
        #pragma unroll
        for (int mi = 0; mi < 4; ++mi)
            #pragma unroll
            for (int r = 0; r < 4; ++r) {
                const int e = mi * 16 + lg * 4 + r;
                *(float*)(smem + e * 1024 + col * 4) = acc[mi][ni][r] + bb;
            }
    }
    __syncthreads();

    // ---- Phase C: LN2 + gelu + dot(w3) + sigmoid
    {
        const int o0 = l * 4;
        f32x4 g2v = *(const f32x4*)(g2 + o0);
        f32x4 e2v = *(const f32x4*)(be2 + o0);
        f32x4 w3v = *(const f32x4*)(w3 + o0);
        float b3s = b3[0];
        #pragma unroll
        for (int el = 0; el < 8; ++el) {
            const int e = w * 8 + el;
            f32x4 h = *(const f32x4*)(smem + e * 1024 + o0 * 4);
            float s  = h[0] + h[1] + h[2] + h[3];
            float sq = h[0]*h[0] + h[1]*h[1] + h[2]*h[2] + h[3]*h[3];
            s = wred_add(s); sq = wred_add(sq);
            float mean = s * (1.0f / 256.0f);
            float rstd = rsqrtf(sq * (1.0f / 256.0f) - mean * mean + 1e-5f);
            float part = 0.0f;
            #pragma unroll
            for (int c = 0; c < 4; ++c) {
                float xx = (h[c] - mean) * rstd * g2v[c] + e2v[c];
                part += gelu_f(xx) * w3v[c];
            }
            part = wred_add(part);
            if (l == 0)
                out[(size_t)b * E_ + eb * 64 + e] = 1.0f / (1.0f + __expf(-(part + b3s)));
        }
    }
}

// ---------------------------------------------------------------- launch
extern "C" void kernel_launch(void* const* d_in, const int* in_sizes, int n_in,
                              void* d_out, int out_size, void* d_ws, size_t ws_size,
                              hipStream_t stream) {
    const float* verts = (const float*)d_in[0];
    const float* wp    = (const float*)d_in[1];
    const float* bp    = (const float*)d_in[2];
    const float* in_w  = (const float*)d_in[3];
    const float* in_b  = (const float*)d_in[4];
    const float* out_w = (const float*)d_in[5];
    const float* out_b = (const float*)d_in[6];
    const float* w1    = (const float*)d_in[7];
    const float* b1    = (const float*)d_in[8];
    const float* g1    = (const float*)d_in[9];
    const float* be1   = (const float*)d_in[10];
    const float* w2    = (const float*)d_in[11];
    const float* b2    = (const float*)d_in[12];
    const float* g2    = (const float*)d_in[13];
    const float* be2   = (const float*)d_in[14];
    const float* w3    = (const float*)d_in[15];
    const float* b3    = (const float*)d_in[16];
    float* out = (float*)d_out;

    const size_t MB = 1 << 20;
    char* W = (char*)d_ws;
    float*    x     = (float*)(W + 0);                 // 2MB
    _Float16* xfh   = (_Float16*)(W + 2*MB);           // 1MB (frag-major)
    _Float16* xfl   = (_Float16*)(W + 3*MB);           // 1MB
    float*    qkv   = (float*)(W + 4*MB);              // 6MB (dead after attn)
    float*    Amat  = (float*)(W + 4*MB);              // 2MB (reuse qkv)
    float*    Bmat  = (float*)(W + 6*MB);              // 2MB
    _Float16* Ahf   = (_Float16*)(W + 8*MB);           // 1MB (frag-major)
    _Float16* Bhf   = (_Float16*)(W + 9*MB);           // 1MB
    _Float16* ctxfh = (_Float16*)(W + 10*MB);          // 1MB (frag-major)
    _Float16* ctxfl = (_Float16*)(W + 11*MB);          // 1MB
    _Float16* w2f   = (_Float16*)(W + 12*MB);          // 256KB
    int2*     etab  = (int2*)(W + 12*MB + 256*1024);   // 256KB
    float2*   statsA= (float2*)(W + 12*MB + 512*1024); // 8KB
    float2*   statsB= (float2*)(W + 12*MB + 520*1024); // 8KB
    _Float16* iwfh  = (_Float16*)(W + 13*MB);          // 1.5MB
    _Float16* iwfl  = (_Float16*)(W + 13*MB + 1536*1024);
    _Float16* owfh  = (_Float16*)(W + 16*MB);          // 0.5MB
    _Float16* owfl  = (_Float16*)(W + 16*MB + 512*1024);
    _Float16* w1fh  = (_Float16*)(W + 17*MB);          // 1MB
    _Float16* w1fl  = (_Float16*)(W + 18*MB);          // 1MB
    float*    P     = (float*)(W + 19*MB);             // 1MB

    k_setup<<<dim3(8832), dim3(256), 0, stream>>>(verts, wp, bp, x, xfh, xfl,
                                                  w2, w2f, etab, in_w, iwfh, iwfl,
                                                  out_w, owfh, owfl, w1, w1fh, w1fl);
    // qkv = x @ in_w^T + in_b
    k_gemm_sp<0><<<dim3(24, 16), dim3(256), 0, stream>>>(xfh, xfl, iwfh, iwfl, in_b, nullptr,
                                                         qkv, nullptr, nullptr, nullptr, nullptr, 1536);
    k_attn<<<dim3(256), dim3(256), 0, stream>>>(qkv, ctxfh, ctxfl);
    // x = x + ctx @ out_w^T + out_b ; refresh xfh/xfl
    k_gemm_sp<1><<<dim3(8, 16), dim3(256), 0, stream>>>(ctxfh, ctxfl, owfh, owfl, out_b, x,
                                                        x, xfh, xfl, nullptr, nullptr, 512);
    // Amat = x @ w1[:, :512]^T + b1 ; Bmat = x @ w1[:, 512:]^T
    k_gemm_sp<2><<<dim3(16, 16), dim3(256), 0, stream>>>(xfh, xfl, w1fh, w1fl, b1, nullptr,
                                                         Amat, Ahf, nullptr, Bmat, Bhf, 1024);
    k_pair_stats<<<dim3(384), dim3(256), 0, stream>>>(Ahf, Bhf, Amat, Bmat, P, statsA, statsB);
    k_edge<<<dim3(B_ * 510), dim3(512), 65536, stream>>>(Amat, Bmat, w2f,
                                                         g1, be1, b2, g2, be2, w3, b3,
                                                         etab, statsA, statsB, P, out);
}

// Round 6
// 265.689 us; speedup vs baseline: 1.2928x; 1.1846x over previous
//
#include <hip/hip_runtime.h>
#include <hip/hip_bf16.h>
#include <hip/hip_fp16.h>

#define B_  4
#define V_  256
#define H_  512
#define E_  32640   // V*(V-1)/2

typedef _Float16 half8 __attribute__((ext_vector_type(8)));
typedef float    f32x4 __attribute__((ext_vector_type(4)));

// Fast erf (Abramowitz-Stegun 7.1.26, |err| <= 1.5e-7), branchless.
__device__ __forceinline__ float gelu_f(float x) {
    float u = x * 0.70710678118654752f;
    float a = fabsf(u);
    float t = __builtin_amdgcn_rcpf(fmaf(0.3275911f, a, 1.0f));
    float poly = t * fmaf(t, fmaf(t, fmaf(t, fmaf(t, 1.061405429f, -1.453152027f),
                                          1.421413741f), -0.284496736f), 0.254829592f);
    float ex = __expf(-u * u);
    float erfa = fmaf(-poly, ex, 1.0f);
    float erfu = copysignf(erfa, u);
    return 0.5f * x * (1.0f + erfu);
}

__device__ __forceinline__ float wred_add(float v) {
    #pragma unroll
    for (int off = 32; off > 0; off >>= 1) v += __shfl_xor(v, off, 64);
    return v;
}

__device__ __forceinline__ void split16(float v, _Float16* hi, _Float16* lo) {
    _Float16 h = (_Float16)v;
    *hi = h; *lo = (_Float16)(v - (float)h);
}

// fragment-major offset for matrix with R rows: element (row, k) -> ((k/8)*R + row)*8 + k%8
__device__ __forceinline__ size_t fmoff(int R, int row, int k) {
    return ((size_t)(k >> 3) * R + row) * 8 + (k & 7);
}

// ---------------------------------------------------------------- one-shot setup
__global__ void k_setup(const float* __restrict__ verts, const float* __restrict__ wp,
                        const float* __restrict__ bp, float* __restrict__ x,
                        _Float16* __restrict__ xfh, _Float16* __restrict__ xfl,
                        const float* __restrict__ w2, _Float16* __restrict__ w2f,
                        int2* __restrict__ etab,
                        const float* __restrict__ in_w, _Float16* __restrict__ iwfh, _Float16* __restrict__ iwfl,
                        const float* __restrict__ out_w, _Float16* __restrict__ owfh, _Float16* __restrict__ owfl,
                        const float* __restrict__ w1, _Float16* __restrict__ w1fh, _Float16* __restrict__ w1fl) {
    int t = blockIdx.x * 256 + threadIdx.x;
    if (t < 524288) {
        int row = t >> 9, k = t & 511;
        const float* vr = verts + row * 3;
        const float* wr = wp + k * 3;
        float val = vr[0] * wr[0] + vr[1] * wr[1] + vr[2] * wr[2] + bp[k];
        x[t] = val;
        size_t fo = fmoff(1024, row, k);
        split16(val, xfh + fo, xfl + fo);
        return;
    }
    t -= 524288;
    if (t < 131072) {
        int col = t >> 9, k = t & 511;
        w2f[fmoff(256, col, k)] = (_Float16)w2[t];
        return;
    }
    t -= 131072;
    if (t < 32640) {
        double disc = (double)(2 * V_ - 1) * (2 * V_ - 1) - 8.0 * (double)t;
        int i = (int)((2 * V_ - 1 - sqrt(disc)) * 0.5);
        if (i < 0) i = 0;
        if (i > V_ - 2) i = V_ - 2;
        while (i < V_ - 2 && (i + 1) * (2 * V_ - 1 - (i + 1)) / 2 <= t) ++i;
        while (i > 0 && i * (2 * V_ - 1 - i) / 2 > t) --i;
        int j = t - i * (2 * V_ - 1 - i) / 2 + i + 1;
        etab[t] = make_int2(i, j);
        return;
    }
    t -= 32640;
    if (t < 786432) {
        int col = t >> 9, k = t & 511;
        size_t fo = fmoff(1536, col, k);
        split16(in_w[t], iwfh + fo, iwfl + fo);
        return;
    }
    t -= 786432;
    if (t < 262144) {
        int col = t >> 9, k = t & 511;
        size_t fo = fmoff(512, col, k);
        split16(out_w[t], owfh + fo, owfl + fo);
        return;
    }
    t -= 262144;
    if (t < 524288) {
        int col = t >> 9, k = t & 511;
        float v = (col < 512) ? w1[col * 1024 + k] : w1[(col - 512) * 1024 + 512 + k];
        size_t fo = fmoff(1024, col, k);
        split16(v, w1fh + fo, w1fl + fo);
    }
}

// ---------------------------------------------------------------- split-fp16 MFMA GEMM (frag-major in)
// MODE 1: C=x(+bias+res), frag split out. MODE 2: Amat/Ahf | Bmat/Bhf.
// MODE 3 (qkv): col<1024 -> QK frag-major [b,h'(16)][dg(8)][tok(256)][8] hi/lo via Fh/Fl;
//               col>=1024 -> V frag-major [b,h(8)][kg(32)][d(64)][8] hi/lo via C2(cast)/F2h.
template<int MODE>
__global__ __launch_bounds__(256) void k_gemm_sp(
        const _Float16* __restrict__ Ahf, const _Float16* __restrict__ Alf,
        const _Float16* __restrict__ Whf, const _Float16* __restrict__ Wlf,
        const float* __restrict__ bias, const float* __restrict__ res,
        float* __restrict__ C, _Float16* __restrict__ Fh, _Float16* __restrict__ Fl,
        float* __restrict__ C2, _Float16* __restrict__ F2h, int N)
{
    const int tid = threadIdx.x;
    const int w = tid >> 6, l = tid & 63;
    const int lr = l & 15, lg = l >> 4;
    const int mg = w >> 1, ng = w & 1;
    const int row0 = blockIdx.y * 64 + mg * 32;
    const int col0 = blockIdx.x * 64 + ng * 32;

    f32x4 acc[2][2] = {};
    for (int kk = 0; kk < 16; ++kk) {
        const int kg = kk * 4 + lg;
        half8 ah[2], al[2], bh[2], bl[2];
        #pragma unroll
        for (int mi = 0; mi < 2; ++mi) {
            size_t off = ((size_t)kg * 1024 + row0 + mi * 16 + lr) * 8;
            ah[mi] = *(const half8*)(Ahf + off);
            al[mi] = *(const half8*)(Alf + off);
        }
        #pragma unroll
        for (int ni = 0; ni < 2; ++ni) {
            size_t off = ((size_t)kg * N + col0 + ni * 16 + lr) * 8;
            bh[ni] = *(const half8*)(Whf + off);
            bl[ni] = *(const half8*)(Wlf + off);
        }
        #pragma unroll
        for (int mi = 0; mi < 2; ++mi)
            #pragma unroll
            for (int ni = 0; ni < 2; ++ni) {
                acc[mi][ni] = __builtin_amdgcn_mfma_f32_16x16x32_f16(ah[mi], bh[ni], acc[mi][ni], 0, 0, 0);
                acc[mi][ni] = __builtin_amdgcn_mfma_f32_16x16x32_f16(ah[mi], bl[ni], acc[mi][ni], 0, 0, 0);
                acc[mi][ni] = __builtin_amdgcn_mfma_f32_16x16x32_f16(al[mi], bh[ni], acc[mi][ni], 0, 0, 0);
            }
    }
    #pragma unroll
    for (int mi = 0; mi < 2; ++mi)
        #pragma unroll
        for (int ni = 0; ni < 2; ++ni)
            #pragma unroll
            for (int r = 0; r < 4; ++r) {
                int row = row0 + mi * 16 + lg * 4 + r;
                int col = col0 + ni * 16 + lr;
                float v = acc[mi][ni][r];
                if (MODE == 1) {
                    size_t idx = (size_t)row * 512 + col;
                    v += bias[col] + res[idx];
                    C[idx] = v;
                    size_t fo = fmoff(1024, row, col);
                    split16(v, Fh + fo, Fl + fo);
                } else if (MODE == 2) {
                    if (col < 512) {
                        size_t idx = (size_t)row * 512 + col;
                        v += bias[col];
                        C[idx] = v;
                        Fh[fmoff(1024, row, col)] = (_Float16)v;
                    } else {
                        int c2 = col - 512;
                        C2[(size_t)row * 512 + c2] = v;
                        F2h[fmoff(1024, row, c2)] = (_Float16)v;
                    }
                } else {  // MODE 3
                    v += bias[col];
                    int bb = row >> 8, tok = row & 255;
                    _Float16 hi = (_Float16)v;
                    _Float16 lo = (_Float16)(v - (float)hi);
                    if (col < 1024) {
                        int hp = col >> 6, d = col & 63;
                        size_t off = (((size_t)(bb * 16 + hp) * 8 + (d >> 3)) * 256 + tok) * 8 + (d & 7);
                        Fh[off] = hi; Fl[off] = lo;
                    } else {
                        int c = col - 1024, hp = c >> 6, d = c & 63;
                        size_t off = (((size_t)(bb * 8 + hp) * 32 + (tok >> 3)) * 64 + d) * 8 + (tok & 7);
                        ((_Float16*)C2)[off] = hi; F2h[off] = lo;
                    }
                }
            }
}

// ---------------------------------------------------------------- MFMA attention
// grid = B*NH*4 (q-blocks of 64), 256 thr = 4 waves; wave w owns 16 q-rows.
// S = QK^T via split-fp16 (fp32-accurate); softmax in registers (C-layout);
// P (hi+lo fp16) bounced through per-wave swizzled LDS; PV via split MFMA.
__global__ __launch_bounds__(256) void k_attn(
        const _Float16* __restrict__ QKh, const _Float16* __restrict__ QKl,
        const _Float16* __restrict__ Vh, const _Float16* __restrict__ Vl,
        _Float16* __restrict__ cfh, _Float16* __restrict__ cfl)
{
    extern __shared__ unsigned char smem[];   // 64KB: per-wave 16KB (Ph 8KB | Pl 8KB)
    const int tid = threadIdx.x;
    const int w = tid >> 6, l = tid & 63;
    const int lr = l & 15, lg = l >> 4;
    const int bh = blockIdx.x >> 2;           // b*8+h
    const int b = bh >> 3, h = bh & 7;
    const int qb = blockIdx.x & 3;
    const int q0 = qb * 64 + w * 16;
    unsigned char* ph_base = smem + w * 16384;
    unsigned char* pl_base = ph_base + 8192;

    const size_t qbase = (size_t)(b * 16 + h) * 8;       // Q at h' = h
    const size_t kbase = (size_t)(b * 16 + 8 + h) * 8;   // K at h' = 8+h
    const size_t vbase = (size_t)(b * 8 + h) * 32;

    // Q A-frags (lane: q-row = lr, d = ks*32 + lg*8 + j)
    half8 qh[2], ql[2];
    #pragma unroll
    for (int ks = 0; ks < 2; ++ks) {
        size_t off = ((qbase + ks * 4 + lg) * 256 + q0 + lr) * 8;
        qh[ks] = *(const half8*)(QKh + off);
        ql[ks] = *(const half8*)(QKl + off);
    }

    // S = Q@K^T : 16 key-tiles, split-fp16 (ah*bh + ah*bl + al*bh)
    f32x4 sc[16];
    #pragma unroll
    for (int kt = 0; kt < 16; ++kt) {
        f32x4 a = {};
        #pragma unroll
        for (int ks = 0; ks < 2; ++ks) {
            size_t off = ((kbase + ks * 4 + lg) * 256 + kt * 16 + lr) * 8;
            half8 kh = *(const half8*)(QKh + off);
            half8 kl = *(const half8*)(QKl + off);
            a = __builtin_amdgcn_mfma_f32_16x16x32_f16(qh[ks], kh, a, 0, 0, 0);
            a = __builtin_amdgcn_mfma_f32_16x16x32_f16(qh[ks], kl, a, 0, 0, 0);
            a = __builtin_amdgcn_mfma_f32_16x16x32_f16(ql[ks], kh, a, 0, 0, 0);
        }
        sc[kt] = a;
    }

    // row max (C-layout: lane holds rows lg*4+r, col kt*16+lr)
    float mr[4] = {-1e30f, -1e30f, -1e30f, -1e30f};
    #pragma unroll
    for (int kt = 0; kt < 16; ++kt)
        #pragma unroll
        for (int r = 0; r < 4; ++r) mr[r] = fmaxf(mr[r], sc[kt][r]);
    #pragma unroll
    for (int off = 1; off < 16; off <<= 1)
        #pragma unroll
        for (int r = 0; r < 4; ++r) mr[r] = fmaxf(mr[r], __shfl_xor(mr[r], off, 64));

    // exp + write P hi/lo to LDS (swizzled) + row sum
    float Ls[4] = {};
    #pragma unroll
    for (int kt = 0; kt < 16; ++kt)
        #pragma unroll
        for (int r = 0; r < 4; ++r) {
            float p = __expf((sc[kt][r] - mr[r]) * 0.125f);
            Ls[r] += p;
            _Float16 hp = (_Float16)p;
            _Float16 lp = (_Float16)(p - (float)hp);
            const int row = lg * 4 + r;
            unsigned off = row * 512 + (((unsigned)(kt * 16 + lr) * 2) ^ ((row & 7) << 4));
            *(_Float16*)(ph_base + off) = hp;
            *(_Float16*)(pl_base + off) = lp;
        }
    #pragma unroll
    for (int off = 1; off < 16; off <<= 1)
        #pragma unroll
        for (int r = 0; r < 4; ++r) Ls[r] += __shfl_xor(Ls[r], off, 64);

    __syncthreads();

    // PV: ctx[16q, 64d], A = P (row = lr, keys ks*32 + lg*8 + j), B = V frag-major
    f32x4 o[4] = {};
    #pragma unroll
    for (int ks = 0; ks < 8; ++ks) {
        unsigned roff = lr * 512 + (((unsigned)(ks * 64 + lg * 16)) ^ ((lr & 7) << 4));
        half8 pah = *(const half8*)(ph_base + roff);
        half8 pal = *(const half8*)(pl_base + roff);
        #pragma unroll
        for (int nt = 0; nt < 4; ++nt) {
            size_t off = ((vbase + ks * 4 + lg) * 64 + nt * 16 + lr) * 8;
            half8 vbh = *(const half8*)(Vh + off);
            half8 vbl = *(const half8*)(Vl + off);
            o[nt] = __builtin_amdgcn_mfma_f32_16x16x32_f16(pah, vbh, o[nt], 0, 0, 0);
            o[nt] = __builtin_amdgcn_mfma_f32_16x16x32_f16(pah, vbl, o[nt], 0, 0, 0);
            o[nt] = __builtin_amdgcn_mfma_f32_16x16x32_f16(pal, vbh, o[nt], 0, 0, 0);
        }
    }

    float Linv[4];
    #pragma unroll
    for (int r = 0; r < 4; ++r) Linv[r] = 1.0f / Ls[r];
    #pragma unroll
    for (int nt = 0; nt < 4; ++nt)
        #pragma unroll
        for (int r = 0; r < 4; ++r) {
            float val = o[nt][r] * Linv[r];
            int row = b * 256 + q0 + lg * 4 + r;
            int col = h * 64 + nt * 16 + lr;
            size_t fo = fmoff(1024, row, col);
            split16(val, cfh + fo, cfl + fo);
        }
}

// ---------------------------------------------------------------- pair dots + row stats (fused)
__global__ __launch_bounds__(256) void k_pair_stats(
        const _Float16* __restrict__ Ahf, const _Float16* __restrict__ Bhf,
        const float* __restrict__ Amat, const float* __restrict__ Bmat,
        float* __restrict__ P, float2* __restrict__ statsA, float2* __restrict__ statsB) {
    const int bid = blockIdx.x;
    const int tid = threadIdx.x;
    if (bid < 256) {
        const int t = bid * 4 + (tid >> 6);
        const int b = t >> 8, tt = t & 255;
        const int i0 = (tt >> 4) * 16, j0 = (tt & 15) * 16;
        const int l = tid & 63, lr = l & 15, lg = l >> 4;
        f32x4 acc = {};
        for (int kk = 0; kk < 16; ++kk) {
            const int kg = kk * 4 + lg;
            half8 af = *(const half8*)(Ahf + ((size_t)kg * 1024 + b * 256 + i0 + lr) * 8);
            half8 bf = *(const half8*)(Bhf + ((size_t)kg * 1024 + b * 256 + j0 + lr) * 8);
            acc = __builtin_amdgcn_mfma_f32_16x16x32_f16(af, bf, acc, 0, 0, 0);
        }
        #pragma unroll
        for (int r = 0; r < 4; ++r)
            P[((size_t)b << 16) + (size_t)(i0 + lg * 4 + r) * 256 + j0 + lr] = acc[r];
    } else {
        const int sid = bid - 256;
        const int slice = tid >> 4, lane = tid & 15;
        const int m = sid * 16 + slice;
        const float* src = (m < 1024 ? Amat + (size_t)m * 512 : Bmat + (size_t)(m - 1024) * 512);
        float s = 0.0f, sq = 0.0f;
        #pragma unroll
        for (int i = 0; i < 8; ++i) {
            f32x4 v = *(const f32x4*)(src + i * 64 + lane * 4);
            s  += v[0] + v[1] + v[2] + v[3];
            sq += v[0]*v[0] + v[1]*v[1] + v[2]*v[2] + v[3]*v[3];
        }
        #pragma unroll
        for (int off = 8; off > 0; off >>= 1) {
            s  += __shfl_xor(s, off, 64);
            sq += __shfl_xor(sq, off, 64);
        }
        if (lane == 0) {
            if (m < 1024) statsA[m] = make_float2(s, sq);
            else          statsB[m - 1024] = make_float2(s, sq);
        }
    }
}

// ---------------------------------------------------------------- fused edge MLP
__global__ __launch_bounds__(512, 4) void k_edge(
        const float* __restrict__ Am, const float* __restrict__ Bm,
        const _Float16* __restrict__ w2f,
        const float* __restrict__ g1, const float* __restrict__ be1,
        const float* __restrict__ b2, const float* __restrict__ g2,
        const float* __restrict__ be2, const float* __restrict__ w3,
        const float* __restrict__ b3, const int2* __restrict__ etab,
        const float2* __restrict__ statsA, const float2* __restrict__ statsB,
        const float* __restrict__ P, float* __restrict__ out)
{
    extern __shared__ unsigned char smem[];   // 65536 B
    const int tid = threadIdx.x;
    const int w = tid >> 6;
    const int l = tid & 63;
    const int bid0 = blockIdx.x;
    const int swz = (bid0 & 7) * 255 + (bid0 >> 3);
    const int b  = swz / 510;
    const int eb = swz % 510;

    // ---- Phase A: g = gelu(LN1(A_i + B_j)) -> fp16 LDS in MFMA-fragment order
    {
        const int el = l >> 3;
        const int kq = l & 7;
        const int e  = w * 8 + el;
        int2 ij = etab[eb * 64 + e];
        float2 sa = statsA[b * 256 + ij.x];
        float2 sb = statsB[b * 256 + ij.y];
        float pij = P[((size_t)b << 16) + ((size_t)ij.x << 8) + ij.y];
        float mean = (sa.x + sb.x) * (1.0f / 512.0f);
        float ex2  = (sa.y + sb.y + 2.0f * pij) * (1.0f / 512.0f);
        float rstd = rsqrtf(ex2 - mean * mean + 1e-5f);
        const float* ar = Am + (((size_t)(b * 256 + ij.x)) << 9);
        const float* br = Bm + (((size_t)(b * 256 + ij.y)) << 9);
        #pragma unroll
        for (int t = 0; t < 8; ++t) {
            const int kg = kq + 8 * t;
            const int k0 = kg * 8;
            f32x4 a0 = *(const f32x4*)(ar + k0);
            f32x4 a1 = *(const f32x4*)(ar + k0 + 4);
            f32x4 c0 = *(const f32x4*)(br + k0);
            f32x4 c1 = *(const f32x4*)(br + k0 + 4);
            f32x4 ga = *(const f32x4*)(g1 + k0);
            f32x4 gb = *(const f32x4*)(g1 + k0 + 4);
            f32x4 ea = *(const f32x4*)(be1 + k0);
            f32x4 ebv= *(const f32x4*)(be1 + k0 + 4);
            half8 hv;
            #pragma unroll
            for (int c = 0; c < 4; ++c) {
                float xa = ((a0[c] + c0[c]) - mean) * rstd * ga[c] + ea[c];
                float xb = ((a1[c] + c1[c]) - mean) * rstd * gb[c] + ebv[c];
                hv[c]     = (_Float16)gelu_f(xa);
                hv[c + 4] = (_Float16)gelu_f(xb);
            }
            *(half8*)(smem + kg * 1024 + ((e ^ (kg & 7)) << 4)) = hv;
        }
    }
    __syncthreads();

    // ---- Phase B: 4 m-tiles x 2 n-tiles per wave (wave owns cols [32w,32w+32))
    f32x4 acc[4][2] = {};
    const int lg = l >> 4, lr = l & 15;
    const int col0 = w * 32;
    #pragma unroll
    for (int kk = 0; kk < 16; ++kk) {
        const int kg = kk * 4 + lg;
        half8 bf[2];
        #pragma unroll
        for (int ni = 0; ni < 2; ++ni)
            bf[ni] = *(const half8*)(w2f + ((size_t)kg * 256 + col0 + ni * 16 + lr) * 8);
        half8 af[4];
        #pragma unroll
        for (int mi = 0; mi < 4; ++mi)
            af[mi] = *(const half8*)(smem + kg * 1024 + (((mi * 16 + lr) ^ (kg & 7)) << 4));
        #pragma unroll
        for (int mi = 0; mi < 4; ++mi)
            #pragma unroll
            for (int ni = 0; ni < 2; ++ni)
                acc[mi][ni] = __builtin_amdgcn_mfma_f32_16x16x32_f16(af[mi], bf[ni], acc[mi][ni], 0, 0, 0);
    }
    __syncthreads();

    // ---- h2 (+b2) -> LDS as [64 edges][256 cols] f32
    #pragma unroll
    for (int ni = 0; ni < 2; ++ni) {
        const int col = col0 + ni * 16 + lr;
        const float bb = b2[col];
        #pragma unroll
        for (int mi = 0; mi < 4; ++mi)
            #pragma unroll
            for (int r = 0; r < 4; ++r) {
                const int e = mi * 16 + lg * 4 + r;
                *(float*)(smem + e * 1024 + col * 4) = acc[mi][ni][r] + bb;
            }
    }
    __syncthreads();

    // ---- Phase C: LN2 + gelu + dot(w3) + sigmoid
    {
        const int o0 = l * 4;
        f32x4 g2v = *(const f32x4*)(g2 + o0);
        f32x4 e2v = *(const f32x4*)(be2 + o0);
        f32x4 w3v = *(const f32x4*)(w3 + o0);
        float b3s = b3[0];
        #pragma unroll
        for (int el = 0; el < 8; ++el) {
            const int e = w * 8 + el;
            f32x4 h = *(const f32x4*)(smem + e * 1024 + o0 * 4);
            float s  = h[0] + h[1] + h[2] + h[3];
            float sq = h[0]*h[0] + h[1]*h[1] + h[2]*h[2] + h[3]*h[3];
            s = wred_add(s); sq = wred_add(sq);
            float mean = s * (1.0f / 256.0f);
            float rstd = rsqrtf(sq * (1.0f / 256.0f) - mean * mean + 1e-5f);
            float part = 0.0f;
            #pragma unroll
            for (int c = 0; c < 4; ++c) {
                float xx = (h[c] - mean) * rstd * g2v[c] + e2v[c];
                part += gelu_f(xx) * w3v[c];
            }
            part = wred_add(part);
            if (l == 0)
                out[(size_t)b * E_ + eb * 64 + e] = 1.0f / (1.0f + __expf(-(part + b3s)));
        }
    }
}

// ---------------------------------------------------------------- launch
extern "C" void kernel_launch(void* const* d_in, const int* in_sizes, int n_in,
                              void* d_out, int out_size, void* d_ws, size_t ws_size,
                              hipStream_t stream) {
    const float* verts = (const float*)d_in[0];
    const float* wp    = (const float*)d_in[1];
    const float* bp    = (const float*)d_in[2];
    const float* in_w  = (const float*)d_in[3];
    const float* in_b  = (const float*)d_in[4];
    const float* out_w = (const float*)d_in[5];
    const float* out_b = (const float*)d_in[6];
    const float* w1    = (const float*)d_in[7];
    const float* b1    = (const float*)d_in[8];
    const float* g1    = (const float*)d_in[9];
    const float* be1   = (const float*)d_in[10];
    const float* w2    = (const float*)d_in[11];
    const float* b2    = (const float*)d_in[12];
    const float* g2    = (const float*)d_in[13];
    const float* be2   = (const float*)d_in[14];
    const float* w3    = (const float*)d_in[15];
    const float* b3    = (const float*)d_in[16];
    float* out = (float*)d_out;

    const size_t MB = 1 << 20;
    char* W = (char*)d_ws;
    float*    x     = (float*)(W + 0);                 // 2MB
    _Float16* xfh   = (_Float16*)(W + 2*MB);           // 1MB (frag-major)
    _Float16* xfl   = (_Float16*)(W + 3*MB);           // 1MB
    _Float16* QKfh  = (_Float16*)(W + 4*MB);           // 2MB (dead after attn)
    _Float16* QKfl  = (_Float16*)(W + 6*MB);           // 2MB
    _Float16* Vfh   = (_Float16*)(W + 8*MB);           // 1MB
    _Float16* Vfl   = (_Float16*)(W + 9*MB);           // 1MB
    float*    Amat  = (float*)(W + 4*MB);              // 2MB (reuse QKf)
    float*    Bmat  = (float*)(W + 6*MB);              // 2MB
    _Float16* Ahf   = (_Float16*)(W + 8*MB);           // 1MB (reuse Vf)
    _Float16* Bhf   = (_Float16*)(W + 9*MB);           // 1MB
    _Float16* ctxfh = (_Float16*)(W + 10*MB);          // 1MB (frag-major)
    _Float16* ctxfl = (_Float16*)(W + 11*MB);          // 1MB
    _Float16* w2f   = (_Float16*)(W + 12*MB);          // 256KB
    int2*     etab  = (int2*)(W + 12*MB + 256*1024);   // 256KB
    float2*   statsA= (float2*)(W + 12*MB + 512*1024); // 8KB
    float2*   statsB= (float2*)(W + 12*MB + 520*1024); // 8KB
    _Float16* iwfh  = (_Float16*)(W + 13*MB);          // 1.5MB
    _Float16* iwfl  = (_Float16*)(W + 13*MB + 1536*1024);
    _Float16* owfh  = (_Float16*)(W + 16*MB);          // 0.5MB
    _Float16* owfl  = (_Float16*)(W + 16*MB + 512*1024);
    _Float16* w1fh  = (_Float16*)(W + 17*MB);          // 1MB
    _Float16* w1fl  = (_Float16*)(W + 18*MB);          // 1MB
    float*    P     = (float*)(W + 19*MB);             // 1MB

    k_setup<<<dim3(8832), dim3(256), 0, stream>>>(verts, wp, bp, x, xfh, xfl,
                                                  w2, w2f, etab, in_w, iwfh, iwfl,
                                                  out_w, owfh, owfl, w1, w1fh, w1fl);
    // qkv -> frag-major fp16 Q/K/V directly (no fp32 qkv)
    k_gemm_sp<3><<<dim3(24, 16), dim3(256), 0, stream>>>(xfh, xfl, iwfh, iwfl, in_b, nullptr,
                                                         nullptr, QKfh, QKfl, (float*)Vfh, Vfl, 1536);
    k_attn<<<dim3(128), dim3(256), 65536, stream>>>(QKfh, QKfl, Vfh, Vfl, ctxfh, ctxfl);
    // x = x + ctx @ out_w^T + out_b ; refresh xfh/xfl
    k_gemm_sp<1><<<dim3(8, 16), dim3(256), 0, stream>>>(ctxfh, ctxfl, owfh, owfl, out_b, x,
                                                        x, xfh, xfl, nullptr, nullptr, 512);
    // Amat = x @ w1[:, :512]^T + b1 ; Bmat = x @ w1[:, 512:]^T
    k_gemm_sp<2><<<dim3(16, 16), dim3(256), 0, stream>>>(xfh, xfl, w1fh, w1fl, b1, nullptr,
                                                         Amat, Ahf, nullptr, Bmat, Bhf, 1024);
    k_pair_stats<<<dim3(384), dim3(256), 0, stream>>>(Ahf, Bhf, Amat, Bmat, P, statsA, statsB);
    k_edge<<<dim3(B_ * 510), dim3(512), 65536, stream>>>(Amat, Bmat, w2f,
                                                         g1, be1, b2, g2, be2, w3, b3,
                                                         etab, statsA, statsB, P, out);
}